// Round 2
// baseline (348.901 us; speedup 1.0000x reference)
//
#include <hip/hip_runtime.h>
#include <stdint.h>

#define WN 4096              // nodes
#define BN 32                // batch
#define LN 96                // gate layers
#define CN 8                 // nodes per block
#define NBLK (WN / CN)       // 512 blocks
#define TPB (CN * BN)        // 256 threads
#define NSTAGE (LN + 1)      // 97 routing stages (top + 96 gates)

#define POISON64 0xAAAAAAAAAAAAAAAAULL

static __device__ __forceinline__ float sigmoid_f(float z) {
    // 1 / (1 + 2^(-z*log2(e)))
    float e = __builtin_amdgcn_exp2f(z * -1.4426950408889634f);
    return __builtin_amdgcn_rcpf(1.0f + e);
}

static __device__ __forceinline__ uint64_t pack2(float a, float b) {
    union { float f[2]; uint64_t u; } u;
    u.f[0] = a; u.f[1] = b;
    return u.u;
}

__global__ __launch_bounds__(TPB, 2) void rh_ring_kernel(
    const float* __restrict__ x,
    const float* __restrict__ w_top,
    const float* __restrict__ b_top,
    const float* __restrict__ w_gate,
    const float* __restrict__ b_gate,
    const float* __restrict__ w_prior,
    const float* __restrict__ b_prior,
    float* __restrict__ out,
    uint64_t* __restrict__ ring)
{
    const int tid  = threadIdx.x;
    const int j    = tid >> 5;     // node within block [0, CN)
    const int b    = tid & 31;     // batch lane
    const int blk  = blockIdx.x;
    const int w    = blk * CN + j; // global node
    const int left = (blk + NBLK - 1) % NBLK;

    __shared__ float4 lodds[2][CN][BN];   // odd outputs staging (parity dbuf)

    float h[8];
    float y[8];

    // ---------------- top layer ----------------
    {
        float xv = x[(size_t)b * WN + w];
        const float4* wt = (const float4*)(w_top + (size_t)w * 32);
        const float4* bt = (const float4*)(b_top + (size_t)w * 8);
        float4 c0 = bt[0], c1 = bt[1];
        float bb[8] = {c0.x, c0.y, c0.z, c0.w, c1.x, c1.y, c1.z, c1.w};
        #pragma unroll
        for (int o = 0; o < 8; ++o) {
            float4 a = wt[o];
            y[o] = sigmoid_f(xv * (a.x + a.y + a.z + a.w) + bb[o]);
        }
    }

    const float4* wg_base = (const float4*)w_gate;
    const float4* bg_base = (const float4*)b_gate;

    float4 wa[16];          // prefetched gate weights (64 floats)
    float4 wb0, wb1;        // prefetched gate bias

    // stages s = 0 (route top) .. 96 (route gate-95 output); gate layer l == s
    #pragma unroll 1
    for (int s = 0; s < NSTAGE; ++s) {
        // 1) publish block-boundary odds to ring (agent-scope atomics; data is
        //    its own ready-flag: sigmoid outputs are in (0,1), never 0xAA.. / 0)
        if (j == CN - 1) {
            uint64_t* slot = ring + (((size_t)s * NBLK + blk) * BN + b) * 2;
            __hip_atomic_store(slot + 0, pack2(y[1], y[3]),
                               __ATOMIC_RELAXED, __HIP_MEMORY_SCOPE_AGENT);
            __hip_atomic_store(slot + 1, pack2(y[5], y[7]),
                               __ATOMIC_RELAXED, __HIP_MEMORY_SCOPE_AGENT);
        }
        // 2) intra-block odds via LDS
        const int par = s & 1;
        lodds[par][j][b] = make_float4(y[1], y[3], y[5], y[7]);

        // 3) prefetch next gate layer's weights BEFORE barrier/spin
        if (s < LN) {
            const float4* wrow = wg_base + ((size_t)s * WN + w) * 16;
            const float4* brow = bg_base + ((size_t)s * WN + w) * 2;
            #pragma unroll
            for (int i = 0; i < 16; ++i) wa[i] = wrow[i];
            wb0 = brow[0];
            wb1 = brow[1];
        }

        __syncthreads();

        // 4) gather neighbor odds
        float od0, od1, od2, od3;
        if (j == 0) {
            const uint64_t* src = ring + (((size_t)s * NBLK + left) * BN + b) * 2;
            uint64_t q0, q1;
            do {
                q0 = __hip_atomic_load(src + 0, __ATOMIC_RELAXED,
                                       __HIP_MEMORY_SCOPE_AGENT);
            } while (q0 == POISON64 || q0 == 0ULL);
            do {
                q1 = __hip_atomic_load(src + 1, __ATOMIC_RELAXED,
                                       __HIP_MEMORY_SCOPE_AGENT);
            } while (q1 == POISON64 || q1 == 0ULL);
            union { uint64_t u; float f[2]; } u0, u1;
            u0.u = q0; u1.u = q1;
            od0 = u0.f[0]; od1 = u0.f[1]; od2 = u1.f[0]; od3 = u1.f[1];
        } else {
            float4 t = lodds[par][j - 1][b];
            od0 = t.x; od1 = t.y; od2 = t.z; od3 = t.w;
        }

        // 5) routing: h[2s] = own evens, h[2s+1] = left-neighbor odds
        //    (global node 0: swapped slots)
        if (w == 0) {
            h[0] = od0;  h[2] = od1;  h[4] = od2;  h[6] = od3;
            h[1] = y[0]; h[3] = y[2]; h[5] = y[4]; h[7] = y[6];
        } else {
            h[0] = y[0]; h[2] = y[2]; h[4] = y[4]; h[6] = y[6];
            h[1] = od0;  h[3] = od1;  h[5] = od2;  h[7] = od3;
        }

        if (s == LN) break;   // h is now the final routed state for the prior

        // 6) gate layer s: y = sigmoid(W h + b) from prefetched weights
        float bb[8] = {wb0.x, wb0.y, wb0.z, wb0.w, wb1.x, wb1.y, wb1.z, wb1.w};
        #pragma unroll
        for (int o = 0; o < 8; ++o) {
            float4 a0 = wa[2 * o], a1 = wa[2 * o + 1];
            float z = bb[o];
            z += a0.x * h[0] + a0.y * h[1] + a0.z * h[2] + a0.w * h[3];
            z += a1.x * h[4] + a1.y * h[5] + a1.z * h[6] + a1.w * h[7];
            y[o] = sigmoid_f(z);
        }
    }

    // ---------------- prior (no sigmoid) ----------------
    {
        const float4* wp = (const float4*)(w_prior + (size_t)w * 8);
        float4 p0 = wp[0], p1 = wp[1];
        float logit = b_prior[w]
            + p0.x * h[0] + p0.y * h[1] + p0.z * h[2] + p0.w * h[3]
            + p1.x * h[4] + p1.y * h[5] + p1.z * h[6] + p1.w * h[7];
        out[(size_t)b * WN + w] = logit;
    }
}

extern "C" void kernel_launch(void* const* d_in, const int* in_sizes, int n_in,
                              void* d_out, int out_size, void* d_ws, size_t ws_size,
                              hipStream_t stream) {
    const float* x       = (const float*)d_in[0];
    const float* w_top   = (const float*)d_in[1];
    const float* b_top   = (const float*)d_in[2];
    const float* w_gate  = (const float*)d_in[3];
    const float* b_gate  = (const float*)d_in[4];
    const float* w_prior = (const float*)d_in[5];
    const float* b_prior = (const float*)d_in[6];
    float* out           = (float*)d_out;
    uint64_t* ring       = (uint64_t*)d_ws;   // needs 97*512*32*16 B = 24.3 MB

    hipLaunchKernelGGL(rh_ring_kernel, dim3(NBLK), dim3(TPB), 0, stream,
                       x, w_top, b_top, w_gate, b_gate, w_prior, b_prior,
                       out, ring);
}